// Round 1
// baseline (545.246 us; speedup 1.0000x reference)
//
#include <hip/hip_runtime.h>
#include <hip/hip_bf16.h>

// Problem constants
#define T_TOK 128
#define N_EXP 8
#define HID   1024
#define INTER 4096

typedef __bf16 bf16x8 __attribute__((ext_vector_type(8)));
typedef __bf16 bf16x4 __attribute__((ext_vector_type(4)));
typedef float  f32x4  __attribute__((ext_vector_type(4)));

// ---------------------------------------------------------------------------
// Kernel 1: routing. softmax over 8 logits -> top2 -> renormalized scales.
// Builds compact per-expert token lists via ballot prefix sums.
// 1 block, 128 threads (one per token, 2 waves).
// ---------------------------------------------------------------------------
__global__ void route_kernel(const float* __restrict__ routing,
                             int* __restrict__ cnt,
                             int* __restrict__ tok,
                             float* __restrict__ scal) {
    int t = threadIdx.x;            // token id 0..127
    int wave = t >> 6, lane = t & 63;

    float l[N_EXP];
#pragma unroll
    for (int e = 0; e < N_EXP; ++e) l[e] = routing[t * N_EXP + e];

    // top-1 (first index wins ties, matching jax.lax.top_k)
    int i1 = 0; float v1 = l[0];
#pragma unroll
    for (int e = 1; e < N_EXP; ++e) if (l[e] > v1) { v1 = l[e]; i1 = e; }
    // top-2
    int i2 = -1; float v2 = -1e30f;
#pragma unroll
    for (int e = 0; e < N_EXP; ++e) if (e != i1 && l[e] > v2) { v2 = l[e]; i2 = e; }

    // renormalized scales: s1 = p1/(p1+p2) = 1/(1+exp(l2-l1))
    float s1 = 1.0f / (1.0f + __expf(v2 - v1));
    float s2 = 1.0f - s1;

    __shared__ unsigned long long wmask[2][N_EXP];
#pragma unroll
    for (int e = 0; e < N_EXP; ++e) {
        bool sel = (i1 == e) || (i2 == e);
        unsigned long long m = __ballot(sel);
        if (lane == 0) wmask[wave][e] = m;
    }
    __syncthreads();
#pragma unroll
    for (int e = 0; e < N_EXP; ++e) {
        bool sel = (i1 == e) || (i2 == e);
        unsigned long long m = __ballot(sel);
        int pre  = __popcll(m & ((1ull << lane) - 1ull));
        int base = (wave == 1) ? __popcll(wmask[0][e]) : 0;
        if (sel) {
            int slot = base + pre;
            tok [e * T_TOK + slot] = t;
            scal[e * T_TOK + slot] = (i1 == e) ? s1 : s2;
        }
        if (t == 0) cnt[e] = __popcll(wmask[0][e]) + __popcll(wmask[1][e]);
    }
}

// ---------------------------------------------------------------------------
// Kernel 2: gather routed hidden rows into compact bf16 A-buffer.
// abuf[e][slot][k] (k contiguous) so MFMA A-fragments are single 16B loads.
// grid = 8*128 blocks of 64 threads; early-exit on padded slots.
// ---------------------------------------------------------------------------
__global__ void prep_kernel(const float* __restrict__ hidden,
                            const int* __restrict__ cnt,
                            const int* __restrict__ tok,
                            __bf16* __restrict__ abuf) {
    int b = blockIdx.x;
    int e = b >> 7, s = b & 127;
    if (s >= cnt[e]) return;
    int t = tok[e * T_TOK + s];
    const float4* src = (const float4*)(hidden + (size_t)t * HID);
    __bf16* dst = abuf + ((size_t)e * T_TOK + s) * HID;
#pragma unroll
    for (int it = 0; it < 4; ++it) {
        int idx = it * 64 + threadIdx.x;       // float4 index 0..255
        float4 v = src[idx];
        bf16x4 pk;
        pk[0] = (__bf16)v.x; pk[1] = (__bf16)v.y;
        pk[2] = (__bf16)v.z; pk[3] = (__bf16)v.w;
        *(bf16x4*)(dst + idx * 4) = pk;
    }
}

__device__ inline bf16x8 cvt8(float4 a, float4 b) {
    bf16x8 r;
    r[0] = (__bf16)a.x; r[1] = (__bf16)a.y; r[2] = (__bf16)a.z; r[3] = (__bf16)a.w;
    r[4] = (__bf16)b.x; r[5] = (__bf16)b.y; r[6] = (__bf16)b.z; r[7] = (__bf16)b.w;
    return r;
}

// ---------------------------------------------------------------------------
// Kernel 3: GEMM1 + swiglu. Per block: one expert, 64 inter indices
// (4 waves x 16). Each wave streams its 16 lin rows + 16 gate rows of w1
// exactly once (fp32 -> bf16 RN in-register), loops over all token m-groups
// with accumulators resident. act[e][slot][i] written as bf16.
// ---------------------------------------------------------------------------
__global__ __launch_bounds__(256) void gemm1_kernel(
    const float* __restrict__ w1,
    const int* __restrict__ cnt,
    const __bf16* __restrict__ abuf,
    __bf16* __restrict__ act) {
    int bx = blockIdx.x;                 // 0..511
    int e  = bx >> 6, nb = bx & 63;
    int wave = threadIdx.x >> 6, lane = threadIdx.x & 63;
    int n0 = nb * 64 + wave * 16;        // inter base for this wave
    int c  = cnt[e];
    int mgs = (c + 15) >> 4;             // token m-groups (<=8)
    int lr = lane & 15;                  // n / m index within tile
    int lq = lane >> 4;                  // k quad

    const float* bl = w1 + ((size_t)e * 2 * INTER + n0 + lr) * HID + lq * 8;
    const float* bg = bl + (size_t)INTER * HID;
    const __bf16* ap = abuf + ((size_t)e * T_TOK + lr) * HID + lq * 8;

    f32x4 accl[8], accg[8];
#pragma unroll
    for (int m = 0; m < 8; ++m) {
        accl[m] = (f32x4){0.f, 0.f, 0.f, 0.f};
        accg[m] = (f32x4){0.f, 0.f, 0.f, 0.f};
    }

    for (int k0 = 0; k0 < HID; k0 += 32) {
        float4 fl0 = *(const float4*)(bl + k0);
        float4 fl1 = *(const float4*)(bl + k0 + 4);
        float4 fg0 = *(const float4*)(bg + k0);
        float4 fg1 = *(const float4*)(bg + k0 + 4);
        bf16x8 BL = cvt8(fl0, fl1);
        bf16x8 BG = cvt8(fg0, fg1);
#pragma unroll
        for (int m = 0; m < 8; ++m) {
            if (m < mgs) {
                bf16x8 A = *(const bf16x8*)(ap + (size_t)m * 16 * HID + k0);
                accl[m] = __builtin_amdgcn_mfma_f32_16x16x32_bf16(A, BL, accl[m], 0, 0, 0);
                accg[m] = __builtin_amdgcn_mfma_f32_16x16x32_bf16(A, BG, accg[m], 0, 0, 0);
            }
        }
    }

    // epilogue: swiglu, store act (C layout: row m = lq*4+r, col n = lr)
#pragma unroll
    for (int m = 0; m < 8; ++m) {
        if (m < mgs) {
#pragma unroll
            for (int r = 0; r < 4; ++r) {
                int slot = m * 16 + lq * 4 + r;
                if (slot < c) {
                    float lin  = accl[m][r];
                    float gate = accg[m][r];
                    float a = lin * (1.0f / (1.0f + __expf(-lin))) * gate;
                    act[((size_t)e * T_TOK + slot) * INTER + n0 + lr] = (__bf16)a;
                }
            }
        }
    }
}

// ---------------------------------------------------------------------------
// Kernel 4: GEMM2 + scaled scatter-add. Per block: one expert, 64 hidden
// cols (4 waves x 16), one K-half (split K=4096 into 2 for occupancy).
// Partial results are coef-scaled and atomicAdd'ed into zeroed d_out.
// ---------------------------------------------------------------------------
__global__ __launch_bounds__(256) void gemm2_kernel(
    const float* __restrict__ w2,
    const int* __restrict__ cnt,
    const int* __restrict__ tok,
    const float* __restrict__ scal,
    const __bf16* __restrict__ act,
    float* __restrict__ out) {
    int bx = blockIdx.x;                 // 0..255 : e(3) | nb(4) | ks(1)
    int ks = bx & 1, nb = (bx >> 1) & 15, e = bx >> 5;
    int wave = threadIdx.x >> 6, lane = threadIdx.x & 63;
    int n0 = nb * 64 + wave * 16;        // hidden col base
    int c  = cnt[e];
    int mgs = (c + 15) >> 4;
    int lr = lane & 15, lq = lane >> 4;

    const float* bp = w2 + ((size_t)e * HID + n0 + lr) * INTER + ks * 2048 + lq * 8;
    const __bf16* ap = act + ((size_t)e * T_TOK + lr) * INTER + ks * 2048 + lq * 8;

    f32x4 acc[8];
#pragma unroll
    for (int m = 0; m < 8; ++m) acc[m] = (f32x4){0.f, 0.f, 0.f, 0.f};

    for (int k0 = 0; k0 < 2048; k0 += 32) {
        float4 f0 = *(const float4*)(bp + k0);
        float4 f1 = *(const float4*)(bp + k0 + 4);
        bf16x8 B = cvt8(f0, f1);
#pragma unroll
        for (int m = 0; m < 8; ++m) {
            if (m < mgs) {
                bf16x8 A = *(const bf16x8*)(ap + (size_t)m * 16 * INTER + k0);
                acc[m] = __builtin_amdgcn_mfma_f32_16x16x32_bf16(A, B, acc[m], 0, 0, 0);
            }
        }
    }

#pragma unroll
    for (int m = 0; m < 8; ++m) {
        if (m < mgs) {
#pragma unroll
            for (int r = 0; r < 4; ++r) {
                int slot = m * 16 + lq * 4 + r;
                if (slot < c) {
                    int   t    = tok [e * T_TOK + slot];
                    float coef = scal[e * T_TOK + slot];
                    atomicAdd(&out[(size_t)t * HID + n0 + lr], coef * acc[m][r]);
                }
            }
        }
    }
}

// ---------------------------------------------------------------------------
// Workspace layout (bytes):
//   [0,32)            cnt[8]
//   [64, 64+4096)     tok_list[8][128]
//   [4160, 8256)      tok_scale[8][128]   (placed at 64+4096)
//   [16384, +2MB)     abuf  bf16 [8][128][1024]
//   [16384+2MB, +8MB) act   bf16 [8][128][4096]
// total ~10.5 MB
// ---------------------------------------------------------------------------
extern "C" void kernel_launch(void* const* d_in, const int* in_sizes, int n_in,
                              void* d_out, int out_size, void* d_ws, size_t ws_size,
                              hipStream_t stream) {
    const float* hidden  = (const float*)d_in[0];
    const float* routing = (const float*)d_in[1];
    const float* w1      = (const float*)d_in[2];
    const float* w2      = (const float*)d_in[3];
    float* out = (float*)d_out;

    char* ws = (char*)d_ws;
    int*    cnt  = (int*)ws;
    int*    tok  = (int*)(ws + 64);
    float*  scal = (float*)(ws + 64 + 4096);
    __bf16* abuf = (__bf16*)(ws + 16384);
    __bf16* act  = (__bf16*)(ws + 16384 + (size_t)2 * 1024 * 1024);

    hipMemsetAsync(d_out, 0, (size_t)out_size * sizeof(float), stream);

    route_kernel<<<1, 128, 0, stream>>>(routing, cnt, tok, scal);
    prep_kernel<<<N_EXP * T_TOK, 64, 0, stream>>>(hidden, cnt, tok, abuf);
    gemm1_kernel<<<N_EXP * 64, 256, 0, stream>>>(w1, cnt, abuf, act);
    gemm2_kernel<<<N_EXP * 32, 256, 0, stream>>>(w2, cnt, tok, scal, act, out);
}

// Round 2
// 483.191 us; speedup vs baseline: 1.1284x; 1.1284x over previous
//
#include <hip/hip_runtime.h>
#include <hip/hip_bf16.h>

// Problem constants
#define T_TOK 128
#define N_EXP 8
#define HID   1024
#define INTER 4096

typedef __bf16 bf16x8 __attribute__((ext_vector_type(8)));
typedef __bf16 bf16x4 __attribute__((ext_vector_type(4)));
typedef float  f32x4  __attribute__((ext_vector_type(4)));

// ---------------------------------------------------------------------------
// Kernel 1: routing. softmax over 8 logits -> top2 -> renormalized scales.
// ---------------------------------------------------------------------------
__global__ void route_kernel(const float* __restrict__ routing,
                             int* __restrict__ cnt,
                             int* __restrict__ tok,
                             float* __restrict__ scal) {
    int t = threadIdx.x;            // token id 0..127
    int wave = t >> 6, lane = t & 63;

    float l[N_EXP];
#pragma unroll
    for (int e = 0; e < N_EXP; ++e) l[e] = routing[t * N_EXP + e];

    int i1 = 0; float v1 = l[0];
#pragma unroll
    for (int e = 1; e < N_EXP; ++e) if (l[e] > v1) { v1 = l[e]; i1 = e; }
    int i2 = -1; float v2 = -1e30f;
#pragma unroll
    for (int e = 0; e < N_EXP; ++e) if (e != i1 && l[e] > v2) { v2 = l[e]; i2 = e; }

    float s1 = 1.0f / (1.0f + __expf(v2 - v1));
    float s2 = 1.0f - s1;

    __shared__ unsigned long long wmask[2][N_EXP];
#pragma unroll
    for (int e = 0; e < N_EXP; ++e) {
        bool sel = (i1 == e) || (i2 == e);
        unsigned long long m = __ballot(sel);
        if (lane == 0) wmask[wave][e] = m;
    }
    __syncthreads();
#pragma unroll
    for (int e = 0; e < N_EXP; ++e) {
        bool sel = (i1 == e) || (i2 == e);
        unsigned long long m = __ballot(sel);
        int pre  = __popcll(m & ((1ull << lane) - 1ull));
        int base = (wave == 1) ? __popcll(wmask[0][e]) : 0;
        if (sel) {
            int slot = base + pre;
            tok [e * T_TOK + slot] = t;
            scal[e * T_TOK + slot] = (i1 == e) ? s1 : s2;
        }
        if (t == 0) cnt[e] = __popcll(wmask[0][e]) + __popcll(wmask[1][e]);
    }
}

// ---------------------------------------------------------------------------
// Kernel 2: gather routed hidden rows into compact bf16 A-buffer.
// ---------------------------------------------------------------------------
__global__ void prep_kernel(const float* __restrict__ hidden,
                            const int* __restrict__ cnt,
                            const int* __restrict__ tok,
                            __bf16* __restrict__ abuf) {
    int b = blockIdx.x;
    int e = b >> 7, s = b & 127;
    if (s >= cnt[e]) return;
    int t = tok[e * T_TOK + s];
    const float4* src = (const float4*)(hidden + (size_t)t * HID);
    __bf16* dst = abuf + ((size_t)e * T_TOK + s) * HID;
#pragma unroll
    for (int it = 0; it < 4; ++it) {
        int idx = it * 64 + threadIdx.x;
        float4 v = src[idx];
        bf16x4 pk;
        pk[0] = (__bf16)v.x; pk[1] = (__bf16)v.y;
        pk[2] = (__bf16)v.z; pk[3] = (__bf16)v.w;
        *(bf16x4*)(dst + idx * 4) = pk;
    }
}

__device__ __forceinline__ bf16x8 cvt8(float4 a, float4 b) {
    bf16x8 r;
    r[0] = (__bf16)a.x; r[1] = (__bf16)a.y; r[2] = (__bf16)a.z; r[3] = (__bf16)a.w;
    r[4] = (__bf16)b.x; r[5] = (__bf16)b.y; r[6] = (__bf16)b.z; r[7] = (__bf16)b.w;
    return r;
}

// ---------------------------------------------------------------------------
// Kernel 3: GEMM1 + swiglu. Branch-free k-loop specialized on m-group count.
// ---------------------------------------------------------------------------
template<int MG>
__device__ __forceinline__ void g1_loop(const float* __restrict__ bl,
                                        const float* __restrict__ bg,
                                        const __bf16* __restrict__ ap,
                                        f32x4* accl, f32x4* accg) {
#pragma unroll 2
    for (int k0 = 0; k0 < HID; k0 += 32) {
        float4 fl0 = *(const float4*)(bl + k0);
        float4 fl1 = *(const float4*)(bl + k0 + 4);
        float4 fg0 = *(const float4*)(bg + k0);
        float4 fg1 = *(const float4*)(bg + k0 + 4);
        bf16x8 A[MG];
#pragma unroll
        for (int m = 0; m < MG; ++m)
            A[m] = *(const bf16x8*)(ap + (size_t)m * 16 * HID + k0);
        bf16x8 BL = cvt8(fl0, fl1);
        bf16x8 BG = cvt8(fg0, fg1);
#pragma unroll
        for (int m = 0; m < MG; ++m) {
            accl[m] = __builtin_amdgcn_mfma_f32_16x16x32_bf16(A[m], BL, accl[m], 0, 0, 0);
            accg[m] = __builtin_amdgcn_mfma_f32_16x16x32_bf16(A[m], BG, accg[m], 0, 0, 0);
        }
    }
}

__global__ __launch_bounds__(256) void gemm1_kernel(
    const float* __restrict__ w1,
    const int* __restrict__ cnt,
    const __bf16* __restrict__ abuf,
    __bf16* __restrict__ act) {
    int bx = blockIdx.x;                 // 0..511
    int e  = bx >> 6, nb = bx & 63;
    int wave = threadIdx.x >> 6, lane = threadIdx.x & 63;
    int n0 = nb * 64 + wave * 16;
    int c  = cnt[e];
    if (c == 0) return;
    int mgs = (c + 15) >> 4;
    int lr = lane & 15;
    int lq = lane >> 4;

    const float* bl = w1 + ((size_t)e * 2 * INTER + n0 + lr) * HID + lq * 8;
    const float* bg = bl + (size_t)INTER * HID;
    const __bf16* ap = abuf + ((size_t)e * T_TOK + lr) * HID + lq * 8;

    f32x4 accl[8], accg[8];
#pragma unroll
    for (int m = 0; m < 8; ++m) {
        accl[m] = (f32x4){0.f, 0.f, 0.f, 0.f};
        accg[m] = (f32x4){0.f, 0.f, 0.f, 0.f};
    }

    switch (mgs) {
        case 1: g1_loop<1>(bl, bg, ap, accl, accg); break;
        case 2: g1_loop<2>(bl, bg, ap, accl, accg); break;
        case 3: g1_loop<3>(bl, bg, ap, accl, accg); break;
        case 4: g1_loop<4>(bl, bg, ap, accl, accg); break;
        case 5: g1_loop<5>(bl, bg, ap, accl, accg); break;
        case 6: g1_loop<6>(bl, bg, ap, accl, accg); break;
        case 7: g1_loop<7>(bl, bg, ap, accl, accg); break;
        default: g1_loop<8>(bl, bg, ap, accl, accg); break;
    }

#pragma unroll
    for (int m = 0; m < 8; ++m) {
        if (m * 16 < c) {
#pragma unroll
            for (int r = 0; r < 4; ++r) {
                int slot = m * 16 + lq * 4 + r;
                if (slot < c) {
                    float lin  = accl[m][r];
                    float gate = accg[m][r];
                    float a = lin * (1.0f / (1.0f + __expf(-lin))) * gate;
                    act[((size_t)e * T_TOK + slot) * INTER + n0 + lr] = (__bf16)a;
                }
            }
        }
    }
}

// ---------------------------------------------------------------------------
// Kernel 4: GEMM2 + scaled scatter-add. K-split 4 for occupancy.
// ---------------------------------------------------------------------------
#define KSPLIT 4
#define KCH (INTER / KSPLIT)   // 1024

template<int MG>
__device__ __forceinline__ void g2_loop(const float* __restrict__ bp,
                                        const __bf16* __restrict__ ap,
                                        f32x4* acc) {
#pragma unroll 2
    for (int k0 = 0; k0 < KCH; k0 += 32) {
        float4 f0 = *(const float4*)(bp + k0);
        float4 f1 = *(const float4*)(bp + k0 + 4);
        bf16x8 A[MG];
#pragma unroll
        for (int m = 0; m < MG; ++m)
            A[m] = *(const bf16x8*)(ap + (size_t)m * 16 * INTER + k0);
        bf16x8 B = cvt8(f0, f1);
#pragma unroll
        for (int m = 0; m < MG; ++m)
            acc[m] = __builtin_amdgcn_mfma_f32_16x16x32_bf16(A[m], B, acc[m], 0, 0, 0);
    }
}

__global__ __launch_bounds__(256) void gemm2_kernel(
    const float* __restrict__ w2,
    const int* __restrict__ cnt,
    const int* __restrict__ tok,
    const float* __restrict__ scal,
    const __bf16* __restrict__ act,
    float* __restrict__ out) {
    int bx = blockIdx.x;                 // 0..511 : e(3) | nb(4) | ks(2)
    int ks = bx & (KSPLIT - 1), nb = (bx >> 2) & 15, e = bx >> 6;
    int wave = threadIdx.x >> 6, lane = threadIdx.x & 63;
    int n0 = nb * 64 + wave * 16;
    int c  = cnt[e];
    if (c == 0) return;
    int mgs = (c + 15) >> 4;
    int lr = lane & 15, lq = lane >> 4;

    const float* bp = w2 + ((size_t)e * HID + n0 + lr) * INTER + ks * KCH + lq * 8;
    const __bf16* ap = act + ((size_t)e * T_TOK + lr) * INTER + ks * KCH + lq * 8;

    f32x4 acc[8];
#pragma unroll
    for (int m = 0; m < 8; ++m) acc[m] = (f32x4){0.f, 0.f, 0.f, 0.f};

    switch (mgs) {
        case 1: g2_loop<1>(bp, ap, acc); break;
        case 2: g2_loop<2>(bp, ap, acc); break;
        case 3: g2_loop<3>(bp, ap, acc); break;
        case 4: g2_loop<4>(bp, ap, acc); break;
        case 5: g2_loop<5>(bp, ap, acc); break;
        case 6: g2_loop<6>(bp, ap, acc); break;
        case 7: g2_loop<7>(bp, ap, acc); break;
        default: g2_loop<8>(bp, ap, acc); break;
    }

#pragma unroll
    for (int m = 0; m < 8; ++m) {
        if (m * 16 < c) {
#pragma unroll
            for (int r = 0; r < 4; ++r) {
                int slot = m * 16 + lq * 4 + r;
                if (slot < c) {
                    int   t    = tok [e * T_TOK + slot];
                    float coef = scal[e * T_TOK + slot];
                    atomicAdd(&out[(size_t)t * HID + n0 + lr], coef * acc[m][r]);
                }
            }
        }
    }
}

// ---------------------------------------------------------------------------
// Workspace layout (bytes):
//   [0,32)            cnt[8]
//   [64, 64+4096)     tok_list[8][128]
//   [4160, 8256)      tok_scale[8][128]
//   [16384, +2MB)     abuf  bf16 [8][128][1024]
//   [16384+2MB, +8MB) act   bf16 [8][128][4096]
// ---------------------------------------------------------------------------
extern "C" void kernel_launch(void* const* d_in, const int* in_sizes, int n_in,
                              void* d_out, int out_size, void* d_ws, size_t ws_size,
                              hipStream_t stream) {
    const float* hidden  = (const float*)d_in[0];
    const float* routing = (const float*)d_in[1];
    const float* w1      = (const float*)d_in[2];
    const float* w2      = (const float*)d_in[3];
    float* out = (float*)d_out;

    char* ws = (char*)d_ws;
    int*    cnt  = (int*)ws;
    int*    tok  = (int*)(ws + 64);
    float*  scal = (float*)(ws + 64 + 4096);
    __bf16* abuf = (__bf16*)(ws + 16384);
    __bf16* act  = (__bf16*)(ws + 16384 + (size_t)2 * 1024 * 1024);

    hipMemsetAsync(d_out, 0, (size_t)out_size * sizeof(float), stream);

    route_kernel<<<1, 128, 0, stream>>>(routing, cnt, tok, scal);
    prep_kernel<<<N_EXP * T_TOK, 64, 0, stream>>>(hidden, cnt, tok, abuf);
    gemm1_kernel<<<N_EXP * 64, 256, 0, stream>>>(w1, cnt, abuf, act);
    gemm2_kernel<<<N_EXP * 16 * KSPLIT, 256, 0, stream>>>(w2, cnt, tok, scal, act, out);
}